// Round 2
// baseline (284.021 us; speedup 1.0000x reference)
//
#include <hip/hip_runtime.h>

// RoiPooling via integral image, channel-last S in workspace.
// S layout: S[y][x][c], y,x in [0,257), c in [0,512). S[y][x][c] = sum fm[c, :y, :x].
// ws usage: 257*257*512*4 bytes = 135,268,352 (~129 MB).

#define CHN   512
#define HDIM  256
#define WDIM  256
#define SP    257   // padded spatial dim of S
#define PADW  260   // LDS row pad: %4==0 keeps 16B alignment for b128; 260%32=4 spreads banks

// ---------------- Kernel Z: zero row 0 and column 0 of S -------------------
__global__ __launch_bounds__(256) void zeroK(float* __restrict__ S) {
    int gid = blockIdx.x * 256 + threadIdx.x;
    const int half = SP * CHN;            // 257*512 = 131584
    if (gid < half) {
        S[gid] = 0.0f;                    // row y=0
    } else {
        int g2 = gid - half;
        if (g2 < half) {
            int y = g2 >> 9;
            int c = g2 & 511;
            S[((size_t)y * SP) * CHN + c] = 0.0f;  // col x=0
        }
    }
}

// ---------------- Kernel A: row prefix scan (shuffle, fp32) + transpose ----
// Block: 256 threads = 4 waves; 32 channels x 256 x; one y.
// Each wave scans 8 channel-rows via wave-shuffle prefix scan (registers),
// writes fp32 prefixes to LDS tile once, then stores transposed (channel-last)
// with float4 (128B per 8 lanes -> full HBM lines).
__global__ __launch_bounds__(256) void rowScanK(const float* __restrict__ fm,
                                               float* __restrict__ S) {
    __shared__ float tile[32][PADW];
    const int t    = threadIdx.x;
    const int lane = t & 63;
    const int wave = t >> 6;              // 0..3
    const int y    = blockIdx.x;          // 0..255
    const int c0   = blockIdx.y * 32;     // 0,32,...,480

    #pragma unroll
    for (int cc = 0; cc < 8; ++cc) {
        const int c = wave * 8 + cc;      // 0..31 within tile
        const float4 v = *(const float4*)(fm + ((size_t)(c0 + c) << 16)
                                             + ((size_t)y << 8) + 4 * lane);
        const float local = ((v.x + v.y) + v.z) + v.w;
        float s = local;
        // inclusive wave scan over lane sums
        #pragma unroll
        for (int d = 1; d < 64; d <<= 1) {
            float u = __shfl_up(s, d, 64);
            if (lane >= d) s += u;
        }
        const float e  = s - local;       // exclusive prefix
        float4 p;
        p.x = e   + v.x;
        p.y = p.x + v.y;
        p.z = p.y + v.z;
        p.w = p.z + v.w;
        *(float4*)&tile[c][4 * lane] = p; // conflict-free b128 (banks 4(c+l)..)
    }
    __syncthreads();

    // Transposed store: thread -> (x, channel-group-of-4). 8 lanes sharing x
    // cover 32 channels = 128B contiguous global store segments.
    #pragma unroll
    for (int it = 0; it < 8; ++it) {
        const int lin = it * 256 + t;
        const int cg  = lin & 7;          // channel group (4 ch)
        const int x   = lin >> 3;         // 0..255
        float4 o;
        o.x = tile[cg * 4 + 0][x];
        o.y = tile[cg * 4 + 1][x];
        o.z = tile[cg * 4 + 2][x];
        o.w = tile[cg * 4 + 3][x];
        *(float4*)(S + (((size_t)(y + 1)) * SP + (x + 1)) * CHN + c0 + cg * 4) = o;
    }
}

// ---------------- Kernel B: column scan (in place, fp64 acc, pipelined) ----
// Thread per (x,c). Software-pipelined: next 16 loads issue before current
// 16 accumulate+store, keeping >=16 loads in flight per wave.
__global__ __launch_bounds__(256) void colScanK(float* __restrict__ S) {
    const int g = blockIdx.x * 256 + threadIdx.x;  // 0 .. 256*512-1
    const int c = g & 511;
    const int x = (g >> 9) + 1;                    // 1..256
    const size_t stride = (size_t)SP * CHN;
    size_t idx = ((size_t)SP + x) * CHN + c;       // y=1

    float buf[16];
    #pragma unroll
    for (int i = 0; i < 16; ++i) buf[i] = S[idx + (size_t)i * stride];

    double acc = 0.0;
    for (int yb = 0; yb < 16; ++yb) {
        float nbuf[16];
        const size_t nidx = idx + 16 * stride;
        if (yb < 15) {
            #pragma unroll
            for (int i = 0; i < 16; ++i) nbuf[i] = S[nidx + (size_t)i * stride];
        }
        #pragma unroll
        for (int i = 0; i < 16; ++i) {
            acc += (double)buf[i];
            S[idx + (size_t)i * stride] = (float)acc;
        }
        idx = nidx;
        #pragma unroll
        for (int i = 0; i < 16; ++i) buf[i] = nbuf[i];
    }
}

// ---------------- Kernel C: 4-corner gather + normalize --------------------
// Block = 128 threads, one region. Blocks ordered n-major so the 4 patches of
// one ROI (which share 9 of 16 corner rows) are co-scheduled for L2 reuse.
__global__ __launch_bounds__(128) void gatherK(const float* __restrict__ S,
                                              const float* __restrict__ roi,
                                              float* __restrict__ out,
                                              float* __restrict__ maskOut,
                                              int N) {
    const int n = blockIdx.x >> 2;
    const int p = blockIdx.x & 3;
    const int b = p * N + n;              // output index, patch-major

    const float xmin = roi[4 * n + 0];
    const float ymin = roi[4 * n + 1];
    const float xmax = roi[4 * n + 2];
    const float ymax = roi[4 * n + 3];

    // pe = 2 (patch_num = 4). Replicate np fp32 op order exactly (no fma).
    const float ixf = (float)(p & 1);
    const float iyf = (float)(p >> 1);
    const float wsv = __fdiv_rn(__fsub_rn(xmax, xmin), 2.0f);
    const float hsv = __fdiv_rn(__fsub_rn(ymax, ymin), 2.0f);
    const float ax  = __fadd_rn(xmin, __fmul_rn(ixf, wsv));
    const float ay  = __fadd_rn(ymin, __fmul_rn(iyf, hsv));

    // clampi = clip(round(v), 0, W-1); np.round = half-to-even = rintf
    const float lim = (float)(WDIM - 1);
    float f;
    f = fminf(fmaxf(rintf(ax), 0.0f), lim);                     const int x0 = (int)f;
    f = fminf(fmaxf(rintf(__fadd_rn(ax, wsv)), 0.0f), lim);     const int x1 = (int)f;
    f = fminf(fmaxf(rintf(ay), 0.0f), lim);                     const int y0 = (int)f;
    f = fminf(fmaxf(rintf(__fadd_rn(ay, hsv)), 0.0f), lim);     const int y1 = (int)f;

    const int cw = x1 - x0;
    const int ch = y1 - y0;
    const int maskv = (cw >= 1 && ch >= 1) ? 1 : 0;
    int areai = cw * ch; if (areai < 1) areai = 1;
    const float areaf = (float)areai;
    const float maskf = (float)maskv;

    const float4* p11 = (const float4*)(S + ((size_t)y1 * SP + x1) * CHN);
    const float4* p01 = (const float4*)(S + ((size_t)y0 * SP + x1) * CHN);
    const float4* p10 = (const float4*)(S + ((size_t)y1 * SP + x0) * CHN);
    const float4* p00 = (const float4*)(S + ((size_t)y0 * SP + x0) * CHN);
    float4* ob = (float4*)(out + (size_t)b * CHN);

    const int t = threadIdx.x;            // 0..127 -> float4 over 512 ch
    const float4 a = p11[t];
    const float4 bq = p01[t];
    const float4 cq = p10[t];
    const float4 dq = p00[t];
    float4 o;
    o.x = __fdiv_rn(((a.x - bq.x) - cq.x) + dq.x, areaf) * maskf;
    o.y = __fdiv_rn(((a.y - bq.y) - cq.y) + dq.y, areaf) * maskf;
    o.z = __fdiv_rn(((a.z - bq.z) - cq.z) + dq.z, areaf) * maskf;
    o.w = __fdiv_rn(((a.w - bq.w) - cq.w) + dq.w, areaf) * maskf;
    ob[t] = o;

    if (t == 0) maskOut[b] = maskf;
}

// ---------------------------------------------------------------------------
extern "C" void kernel_launch(void* const* d_in, const int* in_sizes, int n_in,
                              void* d_out, int out_size, void* d_ws, size_t ws_size,
                              hipStream_t stream) {
    const float* fm  = (const float*)d_in[0];
    const float* roi = (const float*)d_in[1];
    // d_in[2] = patch_num (always 4 here); pe=2 hardcoded in gatherK.

    const int N = in_sizes[1] / 4;     // 4096
    const int B = 4 * N;               // 16384

    float* S       = (float*)d_ws;                       // 257*257*512 floats
    float* out     = (float*)d_out;                      // B*512 pooled
    float* maskOut = out + (size_t)B * CHN;              // B mask values

    zeroK<<<(2 * SP * CHN + 255) / 256, 256, 0, stream>>>(S);

    dim3 gA(HDIM, CHN / 32);
    rowScanK<<<gA, 256, 0, stream>>>(fm, S);

    colScanK<<<(WDIM * CHN) / 256, 256, 0, stream>>>(S);

    gatherK<<<B, 128, 0, stream>>>(S, roi, out, maskOut, N);
}

// Round 3
// 275.890 us; speedup vs baseline: 1.0295x; 1.0295x over previous
//
#include <hip/hip_runtime.h>

// RoiPooling via integral image, channel-last S in workspace.
// S layout: S[y][x][c], y,x in [0,257), c in [0,512). S[y][x][c] = sum fm[c, :y, :x].
// Gather only ever reads indices 0..255 in y,x (clamp to W-1), so row/col 256
// of S are write-only slack.

#define CHN   512
#define HDIM  256
#define WDIM  256
#define SP    257   // padded spatial dim of S
#define PADW  260   // LDS row pad: %4==0 keeps 16B alignment for b128

// ---------------- Kernel A: row prefix scan (shuffle, fp32) + transpose ----
// Block: 256 threads = 4 waves; 32 channels x 256 x; one y.
// Also writes the S zero-borders (col x=0 per row; row y=0 from y==0 blocks),
// replacing the old zeroK dispatch.
__global__ __launch_bounds__(256) void rowScanK(const float* __restrict__ fm,
                                               float* __restrict__ S) {
    __shared__ float tile[32][PADW];
    const int t    = threadIdx.x;
    const int lane = t & 63;
    const int wave = t >> 6;              // 0..3
    const int y    = blockIdx.x;          // 0..255
    const int c0   = blockIdx.y * 32;     // 0,32,...,480

    // Border writes (independent of tile; no sync needed around them).
    const float4 z4 = make_float4(0.f, 0.f, 0.f, 0.f);
    if (t < 8) {  // col x=0, this row: 32 ch = 128B
        *(float4*)(S + ((size_t)(y + 1) * SP) * CHN + c0 + 4 * t) = z4;
    }
    if (y == 0) { // row y=0, x=0..255 for this c-tile
        #pragma unroll
        for (int it = 0; it < 8; ++it) {
            const int lin = it * 256 + t;
            const int cg  = lin & 7;
            const int x   = lin >> 3;
            *(float4*)(S + (size_t)x * CHN + c0 + cg * 4) = z4;
        }
    }

    #pragma unroll
    for (int cc = 0; cc < 8; ++cc) {
        const int c = wave * 8 + cc;      // 0..31 within tile
        const float4 v = *(const float4*)(fm + ((size_t)(c0 + c) << 16)
                                             + ((size_t)y << 8) + 4 * lane);
        const float local = ((v.x + v.y) + v.z) + v.w;
        float s = local;
        #pragma unroll
        for (int d = 1; d < 64; d <<= 1) {
            float u = __shfl_up(s, d, 64);
            if (lane >= d) s += u;
        }
        const float e  = s - local;       // exclusive prefix
        float4 p;
        p.x = e   + v.x;
        p.y = p.x + v.y;
        p.z = p.y + v.z;
        p.w = p.z + v.w;
        *(float4*)&tile[c][4 * lane] = p;
    }
    __syncthreads();

    // Transposed store: 8 lanes sharing x cover 32 channels = 128B segments.
    #pragma unroll
    for (int it = 0; it < 8; ++it) {
        const int lin = it * 256 + t;
        const int cg  = lin & 7;          // channel group (4 ch)
        const int x   = lin >> 3;         // 0..255
        float4 o;
        o.x = tile[cg * 4 + 0][x];
        o.y = tile[cg * 4 + 1][x];
        o.z = tile[cg * 4 + 2][x];
        o.w = tile[cg * 4 + 3][x];
        *(float4*)(S + (((size_t)(y + 1)) * SP + (x + 1)) * CHN + c0 + cg * 4) = o;
    }
}

// ---------------- Kernel B: column scan (in place, fp64 acc, pipelined) ----
__global__ __launch_bounds__(256) void colScanK(float* __restrict__ S) {
    const int g = blockIdx.x * 256 + threadIdx.x;  // 0 .. 256*512-1
    const int c = g & 511;
    const int x = (g >> 9) + 1;                    // 1..256
    const size_t stride = (size_t)SP * CHN;
    size_t idx = ((size_t)SP + x) * CHN + c;       // y=1

    float buf[16];
    #pragma unroll
    for (int i = 0; i < 16; ++i) buf[i] = S[idx + (size_t)i * stride];

    double acc = 0.0;
    for (int yb = 0; yb < 16; ++yb) {
        float nbuf[16];
        const size_t nidx = idx + 16 * stride;
        if (yb < 15) {
            #pragma unroll
            for (int i = 0; i < 16; ++i) nbuf[i] = S[nidx + (size_t)i * stride];
        }
        #pragma unroll
        for (int i = 0; i < 16; ++i) {
            acc += (double)buf[i];
            S[idx + (size_t)i * stride] = (float)acc;
        }
        idx = nidx;
        #pragma unroll
        for (int i = 0; i < 16; ++i) buf[i] = nbuf[i];
    }
}

// ---------------- Kernel C: per-ROI gather (9 shared corners) --------------
// Block = 256 threads, one ROI (4 patches). The 4 sub-boxes' corners lie on a
// 3x3 grid; the shared coords round identically (ax+ws for patch p is the
// bit-exact ax of patch p+1), so 9 corner rows replace 16.
__global__ __launch_bounds__(256) void gatherK(const float* __restrict__ S,
                                              const float* __restrict__ roi,
                                              float* __restrict__ out,
                                              float* __restrict__ maskOut,
                                              int N) {
    const int n = blockIdx.x;
    const float xmin = roi[4 * n + 0];
    const float ymin = roi[4 * n + 1];
    const float xmax = roi[4 * n + 2];
    const float ymax = roi[4 * n + 3];

    // Replicate np fp32 op order exactly (no fma contraction).
    const float wsv = __fdiv_rn(__fsub_rn(xmax, xmin), 2.0f);
    const float hsv = __fdiv_rn(__fsub_rn(ymax, ymin), 2.0f);
    const float ax1 = __fadd_rn(xmin, wsv);   // == __fadd_rn(xmin,__fmul_rn(1,wsv))
    const float ay1 = __fadd_rn(ymin, hsv);
    const float lim = (float)(WDIM - 1);

    int rx[3], ry[3];
    rx[0] = (int)fminf(fmaxf(rintf(xmin), 0.0f), lim);
    rx[1] = (int)fminf(fmaxf(rintf(ax1), 0.0f), lim);
    rx[2] = (int)fminf(fmaxf(rintf(__fadd_rn(ax1, wsv)), 0.0f), lim);
    ry[0] = (int)fminf(fmaxf(rintf(ymin), 0.0f), lim);
    ry[1] = (int)fminf(fmaxf(rintf(ay1), 0.0f), lim);
    ry[2] = (int)fminf(fmaxf(rintf(__fadd_rn(ay1, hsv)), 0.0f), lim);

    const int t = threadIdx.x;            // c-pair index: channels 2t, 2t+1
    float2 g[3][3];
    #pragma unroll
    for (int j = 0; j < 3; ++j)
        #pragma unroll
        for (int i = 0; i < 3; ++i)
            g[j][i] = *(const float2*)(S + ((size_t)ry[j] * SP + rx[i]) * CHN + 2 * t);

    float m[4];
    #pragma unroll
    for (int p = 0; p < 4; ++p) {
        const int ix = p & 1, iy = p >> 1;
        const int cw = rx[ix + 1] - rx[ix];
        const int ch = ry[iy + 1] - ry[iy];
        const int maskv = (cw >= 1 && ch >= 1) ? 1 : 0;
        int areai = cw * ch; if (areai < 1) areai = 1;
        const float areaf = (float)areai;
        const float maskf = (float)maskv;
        m[p] = maskf;

        const float2 s11 = g[iy + 1][ix + 1];
        const float2 s01 = g[iy][ix + 1];
        const float2 s10 = g[iy + 1][ix];
        const float2 s00 = g[iy][ix];
        float2 o;  // reference order: ((S11 - S01) - S10) + S00, /area, *mask
        o.x = __fdiv_rn(((s11.x - s01.x) - s10.x) + s00.x, areaf) * maskf;
        o.y = __fdiv_rn(((s11.y - s01.y) - s10.y) + s00.y, areaf) * maskf;
        *(float2*)(out + ((size_t)p * N + n) * CHN + 2 * t) = o;
    }
    if (t < 4) maskOut[(size_t)t * N + n] = m[t];
}

// ---------------------------------------------------------------------------
extern "C" void kernel_launch(void* const* d_in, const int* in_sizes, int n_in,
                              void* d_out, int out_size, void* d_ws, size_t ws_size,
                              hipStream_t stream) {
    const float* fm  = (const float*)d_in[0];
    const float* roi = (const float*)d_in[1];
    // d_in[2] = patch_num (always 4 here); pe=2 hardcoded.

    const int N = in_sizes[1] / 4;     // 4096
    const int B = 4 * N;               // 16384

    float* S       = (float*)d_ws;                       // 257*257*512 floats
    float* out     = (float*)d_out;                      // B*512 pooled
    float* maskOut = out + (size_t)B * CHN;              // B mask values

    dim3 gA(HDIM, CHN / 32);
    rowScanK<<<gA, 256, 0, stream>>>(fm, S);

    colScanK<<<(WDIM * CHN) / 256, 256, 0, stream>>>(S);

    gatherK<<<N, 256, 0, stream>>>(S, roi, out, maskOut, N);
}